// Round 4
// baseline (643.777 us; speedup 1.0000x reference)
//
#include <hip/hip_runtime.h>

#define NDET 4096
#define NMEM 8192
#define DEMB 256
#define CAP  64

static __device__ __forceinline__ float sim_val(float f, float rm, float rs,
                                                float cm, float cs, bool same) {
  if (!same) return 0.0f;
  return 0.5f * (expf(f - rm) / rs + expf(f - cm) / cs);
}

// ---------- 1. stable descending rank sort ----------
__global__ __launch_bounds__(256) void k_sort(const float* __restrict__ scores,
                                              const int* __restrict__ cls,
                                              const float* __restrict__ det,
                                              int* order, float* sscore, int* scls,
                                              float* sboxes) {
  __shared__ float s[NDET];
  int tid = threadIdx.x;
  for (int i = tid; i < NDET; i += 256) s[i] = scores[i];
  __syncthreads();
  int i = blockIdx.x * 256 + tid;
  float si = s[i];
  int rank = 0;
  for (int j = 0; j < NDET; ++j) {
    float sj = s[j];
    rank += (sj > si) || (sj == si && j < i);
  }
  order[rank] = i;
  sscore[rank] = si;
  scls[rank] = cls[i];
  ((float4*)sboxes)[rank] = ((const float4*)det)[i];
}

// ---------- 2. gather sorted embeddings ----------
__global__ __launch_bounds__(256) void k_gather(const float* __restrict__ emb,
                                                const int* __restrict__ order,
                                                float* A) {
  int idx = blockIdx.x * 256 + threadIdx.x;  // N*64 threads
  int r = idx >> 6, lane = idx & 63;
  int o = order[r];
  ((float4*)A)[(size_t)r * 64 + lane] = ((const float4*)emb)[(size_t)o * 64 + lane];
}

// ---------- 3. NMS validity (all j < i suppress, as in source) ----------
__global__ __launch_bounds__(256) void k_valid(const float* __restrict__ sbox,
                                               const float* __restrict__ sscore,
                                               int* svalid) {
  int i = blockIdx.x, tid = threadIdx.x;
  float4 bi = ((const float4*)sbox)[i];
  float thr = (sscore[i] < 0.3f) ? 0.3f : 0.7f;
  float ai = fmaxf(bi.z - bi.x, 0.f) * fmaxf(bi.w - bi.y, 0.f);
  __shared__ int flag;
  if (tid == 0) flag = 0;
  __syncthreads();
  int any = 0;
  for (int j = tid; j < i; j += 256) {
    float4 bj = ((const float4*)sbox)[j];
    float aj = fmaxf(bj.z - bj.x, 0.f) * fmaxf(bj.w - bj.y, 0.f);
    float lx = fmaxf(bi.x, bj.x), ly = fmaxf(bi.y, bj.y);
    float rx = fminf(bi.z, bj.z), ry = fminf(bi.w, bj.w);
    float w = fmaxf(rx - lx, 0.f), h = fmaxf(ry - ly, 0.f);
    float inter = w * h;
    float den = fmaxf(ai + aj - inter, 1e-6f);
    any |= ((inter / den) > thr);
  }
  if (any) atomicOr(&flag, 1);
  __syncthreads();
  if (tid == 0) svalid[i] = flag ? 0 : 1;
}

// ---------- 4. zero candidate counters ----------
__global__ __launch_bounds__(256) void k_zero(int* __restrict__ ccnt) {
  ccnt[blockIdx.x * 256 + threadIdx.x] = 0;
}

// ---------- 5. GEMM: feats (fp32, into d_out sims region) + tile stats ----------
__global__ __launch_bounds__(256) void k_gemm1(const float* __restrict__ A,
                                               const float* __restrict__ B,
                                               const int* __restrict__ svalid,
                                               float2* __restrict__ rowpart,
                                               float2* __restrict__ colpart,
                                               float* __restrict__ feats) {
  __shared__ float As[32][132];
  __shared__ float Bs[32][132];
  __shared__ float red[128][17];
  __shared__ float tmax[128];
  __shared__ unsigned char vrow[128];
  const int tid = threadIdx.x;
  const int tx = tid & 15, ty = tid >> 4;
  const int j0 = blockIdx.x * 128, i0 = blockIdx.y * 128;
  if (tid < 128) vrow[tid] = (unsigned char)svalid[i0 + tid];
  float acc[8][8];
#pragma unroll
  for (int u = 0; u < 8; ++u)
#pragma unroll
    for (int v = 0; v < 8; ++v) acc[u][v] = 0.f;

  for (int kt = 0; kt < DEMB / 32; ++kt) {
    const int k0 = kt * 32;
    float4 av[4], bv[4];
    int rr[4], cc[4];
#pragma unroll
    for (int e = 0; e < 4; ++e) {
      int f = e * 256 + tid;
      rr[e] = f >> 3;
      cc[e] = (f & 7) << 2;
      av[e] = *(const float4*)(A + (size_t)(i0 + rr[e]) * DEMB + k0 + cc[e]);
      bv[e] = *(const float4*)(B + (size_t)(j0 + rr[e]) * DEMB + k0 + cc[e]);
    }
    __syncthreads();
#pragma unroll
    for (int e = 0; e < 4; ++e) {
      As[cc[e] + 0][rr[e]] = av[e].x;
      As[cc[e] + 1][rr[e]] = av[e].y;
      As[cc[e] + 2][rr[e]] = av[e].z;
      As[cc[e] + 3][rr[e]] = av[e].w;
      Bs[cc[e] + 0][rr[e]] = bv[e].x;
      Bs[cc[e] + 1][rr[e]] = bv[e].y;
      Bs[cc[e] + 2][rr[e]] = bv[e].z;
      Bs[cc[e] + 3][rr[e]] = bv[e].w;
    }
    __syncthreads();
#pragma unroll
    for (int kk = 0; kk < 32; ++kk) {
      float4 a0 = *(const float4*)&As[kk][ty * 8];
      float4 a1 = *(const float4*)&As[kk][ty * 8 + 4];
      float4 b0 = *(const float4*)&Bs[kk][tx * 8];
      float4 b1 = *(const float4*)&Bs[kk][tx * 8 + 4];
      float a[8] = {a0.x, a0.y, a0.z, a0.w, a1.x, a1.y, a1.z, a1.w};
      float b[8] = {b0.x, b0.y, b0.z, b0.w, b1.x, b1.y, b1.z, b1.w};
#pragma unroll
      for (int u = 0; u < 8; ++u)
#pragma unroll
        for (int v = 0; v < 8; ++v) acc[u][v] = __builtin_fmaf(a[u], b[v], acc[u][v]);
    }
  }
  // ---- store raw feats (fp32) into the sims output region ----
#pragma unroll
  for (int u = 0; u < 8; ++u) {
    int row = i0 + ty * 8 + u;
    float4 o0 = {acc[u][0], acc[u][1], acc[u][2], acc[u][3]};
    float4 o1 = {acc[u][4], acc[u][5], acc[u][6], acc[u][7]};
    *(float4*)(feats + (size_t)row * NMEM + j0 + tx * 8) = o0;
    *(float4*)(feats + (size_t)row * NMEM + j0 + tx * 8 + 4) = o1;
  }
  __syncthreads();
  // ---- row stats: exact max-then-sum within tile ----
#pragma unroll
  for (int u = 0; u < 8; ++u) {
    float m = acc[u][0];
#pragma unroll
    for (int v = 1; v < 8; ++v) m = fmaxf(m, acc[u][v]);
    red[ty * 8 + u][tx] = m;
  }
  __syncthreads();
  if (tid < 128) {
    float m = red[tid][0];
#pragma unroll
    for (int t = 1; t < 16; ++t) m = fmaxf(m, red[tid][t]);
    tmax[tid] = m;
  }
  __syncthreads();
#pragma unroll
  for (int u = 0; u < 8; ++u) {
    float m = tmax[ty * 8 + u], s = 0.f;
#pragma unroll
    for (int v = 0; v < 8; ++v) s += expf(acc[u][v] - m);
    red[ty * 8 + u][tx] = s;
  }
  __syncthreads();
  if (tid < 128) {
    float s = 0.f;
#pragma unroll
    for (int t = 0; t < 16; ++t) s += red[tid][t];
    rowpart[(size_t)(i0 + tid) * 64 + blockIdx.x] = make_float2(tmax[tid], s);
  }
  __syncthreads();
  // ---- col stats: valid rows only ----
#pragma unroll
  for (int v = 0; v < 8; ++v) {
    float m = -INFINITY;
#pragma unroll
    for (int u = 0; u < 8; ++u)
      if (vrow[ty * 8 + u]) m = fmaxf(m, acc[u][v]);
    red[tx * 8 + v][ty] = m;
  }
  __syncthreads();
  if (tid < 128) {
    float m = red[tid][0];
#pragma unroll
    for (int t = 1; t < 16; ++t) m = fmaxf(m, red[tid][t]);
    tmax[tid] = m;
  }
  __syncthreads();
#pragma unroll
  for (int v = 0; v < 8; ++v) {
    float m = tmax[tx * 8 + v], s = 0.f;
    if (m > -INFINITY) {
#pragma unroll
      for (int u = 0; u < 8; ++u)
        if (vrow[ty * 8 + u]) s += expf(acc[u][v] - m);
    }
    red[tx * 8 + v][ty] = s;
  }
  __syncthreads();
  if (tid < 128) {
    float s = 0.f;
#pragma unroll
    for (int t = 0; t < 16; ++t) s += red[tid][t];
    colpart[(size_t)(j0 + tid) * 32 + blockIdx.y] = make_float2(tmax[tid], s);
  }
}

// ---------- 6. merge stats (fixed chunk order, deterministic) ----------
__global__ __launch_bounds__(256) void k_rowmerge(const float2* __restrict__ rowpart,
                                                  float* rmax, float* rsum) {
  int r = blockIdx.x * 256 + threadIdx.x;
  float M = -INFINITY;
  for (int c = 0; c < 64; ++c) M = fmaxf(M, rowpart[(size_t)r * 64 + c].x);
  float s = 0.f;
  for (int c = 0; c < 64; ++c) {
    float2 p = rowpart[(size_t)r * 64 + c];
    s += p.y * expf(p.x - M);
  }
  rmax[r] = M;
  rsum[r] = s;
}

__global__ __launch_bounds__(256) void k_colmerge(const float2* __restrict__ colpart,
                                                  float* cmax, float* csum) {
  int c = blockIdx.x * 256 + threadIdx.x;
  float M = -INFINITY;
  for (int b = 0; b < 32; ++b) {
    float2 p = colpart[(size_t)c * 32 + b];
    if (p.y > 0.f) M = fmaxf(M, p.x);
  }
  float s = 0.f;
  for (int b = 0; b < 32; ++b) {
    float2 p = colpart[(size_t)c * 32 + b];
    if (p.y > 0.f) s += p.y * expf(p.x - M);
  }
  cmax[c] = M;
  csum[c] = s;
}

// ---------- 7. in-place transform feats -> sims (fp32) + candidates ----------
__global__ __launch_bounds__(256) void k_transform(float* __restrict__ sims,
                                                   const float* __restrict__ rmax,
                                                   const float* __restrict__ rsum,
                                                   const float* __restrict__ cmax,
                                                   const float* __restrict__ csum,
                                                   const int* __restrict__ scls,
                                                   const int* __restrict__ mcls,
                                                   const int* __restrict__ svalid,
                                                   float* __restrict__ cval,
                                                   int* __restrict__ cidx,
                                                   int* __restrict__ ccnt) {
  const int r = blockIdx.x, tid = threadIdx.x;
  float* row = sims + (size_t)r * NMEM;
  if (!svalid[r]) {
    float4 z = {0.f, 0.f, 0.f, 0.f};
#pragma unroll
    for (int it = 0; it < 8; ++it) *(float4*)(row + it * 1024 + tid * 4) = z;
    return;
  }
  const float rm = rmax[r], rs = rsum[r];
  const int rc = scls[r];
#pragma unroll
  for (int it = 0; it < 8; ++it) {
    int j = it * 1024 + tid * 4;
    float4 f = *(const float4*)(row + j);
    float4 o;
    o.x = sim_val(f.x, rm, rs, cmax[j + 0], csum[j + 0], rc == mcls[j + 0]);
    o.y = sim_val(f.y, rm, rs, cmax[j + 1], csum[j + 1], rc == mcls[j + 1]);
    o.z = sim_val(f.z, rm, rs, cmax[j + 2], csum[j + 2], rc == mcls[j + 2]);
    o.w = sim_val(f.w, rm, rs, cmax[j + 3], csum[j + 3], rc == mcls[j + 3]);
    *(float4*)(row + j) = o;
    float vs[4] = {o.x, o.y, o.z, o.w};
#pragma unroll
    for (int q = 0; q < 4; ++q) {
      if (vs[q] > 0.5f) {
        int ps = atomicAdd(&ccnt[r], 1);
        if (ps < CAP) {
          cval[(size_t)r * CAP + ps] = vs[q];
          cidx[(size_t)r * CAP + ps] = j + q;
        }
      }
    }
  }
}

// ---------- 8. greedy matching + new tracks + un-permute ----------
__global__ __launch_bounds__(256) void k_match(
    float* __restrict__ cval, int* __restrict__ cidx, const int* __restrict__ ccnt,
    const float* __restrict__ sscore, const int* __restrict__ svalid,
    const int* __restrict__ order, const int* __restrict__ mtrack,
    const int* __restrict__ ntptr, const float* __restrict__ sims,
    float* __restrict__ out) {
  const int tid = threadIdx.x;
  __shared__ float sc[NDET];
  __shared__ unsigned char vl[NDET];
  __shared__ unsigned short cnt_s[NDET];
  __shared__ int ids_s[NDET];
  __shared__ unsigned int taken[NMEM / 32];
  __shared__ unsigned short rlist[NDET];
  __shared__ int part[256];
  __shared__ int nR_s;
  __shared__ float rv[256];
  __shared__ int ri[256];

  for (int r = tid; r < NDET; r += 256) {
    sc[r] = sscore[r];
    vl[r] = (unsigned char)svalid[r];
    int c = ccnt[r];
    cnt_s[r] = (unsigned short)(c > 65535 ? 65535 : c);
    ids_s[r] = -1;
  }
  taken[tid] = 0u;
  __syncthreads();
  // per-row candidate sort (val desc, idx asc) for rows with 0 < cnt <= CAP
  for (int r = tid; r < NDET; r += 256) {
    int n = cnt_s[r];
    if (n == 0 || n > CAP) continue;
    float* cv = cval + (size_t)r * CAP;
    int* ci = cidx + (size_t)r * CAP;
    for (int a = 1; a < n; ++a) {
      float v = cv[a];
      int id = ci[a];
      int b = a - 1;
      while (b >= 0 && (cv[b] < v || (cv[b] == v && ci[b] > id))) {
        cv[b + 1] = cv[b];
        ci[b + 1] = ci[b];
        --b;
      }
      cv[b + 1] = v;
      ci[b + 1] = id;
    }
  }
  __syncthreads();
  // ascending list of rows with candidates
  const int base = tid * 16;
  int cn = 0;
  for (int k = 0; k < 16; ++k) cn += (cnt_s[base + k] > 0);
  part[tid] = cn;
  __syncthreads();
  if (tid == 0) {
    int run = 0;
    for (int t = 0; t < 256; ++t) { int v = part[t]; part[t] = run; run += v; }
    nR_s = run;
  }
  __syncthreads();
  {
    int pos = part[tid];
    for (int k = 0; k < 16; ++k) {
      int r = base + k;
      if (cnt_s[r] > 0) rlist[pos++] = (unsigned short)r;
    }
  }
  __syncthreads();
  const int nR = nR_s;

  for (int t = 0; t < nR; ++t) {
    const int r = rlist[t];
    const int c = cnt_s[r];
    if (c <= CAP) {
      if (tid == 0) {
        float conf = 0.f;
        int ind = -1;
        for (int q = 0; q < c; ++q) {
          int j = cidx[(size_t)r * CAP + q];
          if (!((taken[j >> 5] >> (j & 31)) & 1u)) {
            conf = cval[(size_t)r * CAP + q];
            ind = j;
            break;
          }
        }
        if (ind >= 0 && conf > 0.5f) {
          int cur = mtrack[ind];
          if (cur > -1) {
            if (sc[r] > 0.3f) { ids_s[r] = cur; taken[ind >> 5] |= (1u << (ind & 31)); }
          } else ids_s[r] = -2;
        }
      }
      __syncthreads();
    } else {
      // overflow fallback: argmax over stored sims row with taken zeroed
      const float* srow = sims + (size_t)r * NMEM;
      float bv = -1.f;
      int bi = 1 << 30;
      for (int j = tid; j < NMEM; j += 256) {
        float v = ((taken[j >> 5] >> (j & 31)) & 1u) ? 0.f : srow[j];
        if (v > bv || (v == bv && j < bi)) { bv = v; bi = j; }
      }
      rv[tid] = bv;
      ri[tid] = bi;
      __syncthreads();
      for (int off = 128; off > 0; off >>= 1) {
        if (tid < off) {
          float v2 = rv[tid + off];
          int i2 = ri[tid + off];
          if (v2 > rv[tid] || (v2 == rv[tid] && i2 < ri[tid])) { rv[tid] = v2; ri[tid] = i2; }
        }
        __syncthreads();
      }
      if (tid == 0) {
        float conf = rv[0];
        int ind = ri[0];
        if (conf > 0.5f) {
          int cur = mtrack[ind];
          if (cur > -1) {
            if (sc[r] > 0.3f) { ids_s[r] = cur; taken[ind >> 5] |= (1u << (ind & 31)); }
          } else ids_s[r] = -2;
        }
      }
      __syncthreads();
    }
  }

  // new tracks: cumsum over sorted order
  int cntNew = 0;
  for (int k = 0; k < 16; ++k) {
    int r = base + k;
    cntNew += (ids_s[r] == -1 && sc[r] > 0.7f && vl[r]);
  }
  part[tid] = cntNew;
  __syncthreads();
  if (tid == 0) {
    int run = 0;
    for (int t2 = 0; t2 < 256; ++t2) { int v = part[t2]; part[t2] = run; run += v; }
  }
  __syncthreads();
  const int nt = ntptr[0];
  int off2 = part[tid];
  for (int k = 0; k < 16; ++k) {
    int r = base + k;
    if (ids_s[r] == -1 && sc[r] > 0.7f && vl[r]) { ids_s[r] = nt + off2; off2++; }
  }
  __syncthreads();
  // un-permute; outputs are FLOAT32
  for (int r = tid; r < NDET; r += 256) {
    int o = order[r];
    out[o] = (float)ids_s[r];
    out[NDET + o] = vl[r] ? 1.0f : 0.0f;
  }
}

extern "C" void kernel_launch(void* const* d_in, const int* in_sizes, int n_in,
                              void* d_out, int out_size, void* d_ws, size_t ws_size,
                              hipStream_t stream) {
  const float* det = (const float*)d_in[0];
  const float* scores = (const float*)d_in[1];
  const int* cls = (const int*)d_in[2];
  const float* emb = (const float*)d_in[3];
  const float* memo = (const float*)d_in[4];
  const int* mcls = (const int*)d_in[5];
  const int* mtrack = (const int*)d_in[6];
  const int* ntptr = (const int*)d_in[7];
  float* out = (float*)d_out;               // fp32 outputs: [ids | valid | sims]
  float* feats = out + 2 * NDET;            // sims region doubles as feats scratch

  // ---- workspace: ~10.25 MB ----
  char* ws = (char*)d_ws;
  size_t o_A = 0;                                        // 4 MB
  size_t o_order = o_A + (size_t)NDET * DEMB * 4;
  size_t o_sscore = o_order + NDET * 4;
  size_t o_scls = o_sscore + NDET * 4;
  size_t o_svalid = o_scls + NDET * 4;
  size_t o_sbox = o_svalid + NDET * 4;
  size_t o_rowpart = o_sbox + NDET * 16;                 // 2 MB
  size_t o_colpart = o_rowpart + (size_t)NDET * 64 * 8;  // 2 MB
  size_t o_rmax = o_colpart + (size_t)NMEM * 32 * 8;
  size_t o_rsum = o_rmax + NDET * 4;
  size_t o_cmax = o_rsum + NDET * 4;
  size_t o_csum = o_cmax + NMEM * 4;
  size_t o_cval = o_csum + NMEM * 4;                     // 1 MB
  size_t o_cidx = o_cval + (size_t)NDET * CAP * 4;       // 1 MB
  size_t o_ccnt = o_cidx + (size_t)NDET * CAP * 4;       // 16 KB

  float* A = (float*)(ws + o_A);
  int* order = (int*)(ws + o_order);
  float* sscore = (float*)(ws + o_sscore);
  int* scls = (int*)(ws + o_scls);
  int* svalid = (int*)(ws + o_svalid);
  float* sbox = (float*)(ws + o_sbox);
  float2* rowpart = (float2*)(ws + o_rowpart);
  float2* colpart = (float2*)(ws + o_colpart);
  float* rmax = (float*)(ws + o_rmax);
  float* rsum = (float*)(ws + o_rsum);
  float* cmax = (float*)(ws + o_cmax);
  float* csum = (float*)(ws + o_csum);
  float* cval = (float*)(ws + o_cval);
  int* cidx = (int*)(ws + o_cidx);
  int* ccnt = (int*)(ws + o_ccnt);

  k_sort<<<NDET / 256, 256, 0, stream>>>(scores, cls, det, order, sscore, scls, sbox);
  k_gather<<<NDET * 64 / 256, 256, 0, stream>>>(emb, order, A);
  k_valid<<<NDET, 256, 0, stream>>>(sbox, sscore, svalid);
  k_zero<<<NDET / 256, 256, 0, stream>>>(ccnt);
  k_gemm1<<<dim3(NMEM / 128, NDET / 128), 256, 0, stream>>>(A, memo, svalid, rowpart,
                                                            colpart, feats);
  k_rowmerge<<<NDET / 256, 256, 0, stream>>>(rowpart, rmax, rsum);
  k_colmerge<<<NMEM / 256, 256, 0, stream>>>(colpart, cmax, csum);
  k_transform<<<NDET, 256, 0, stream>>>(feats, rmax, rsum, cmax, csum, scls, mcls,
                                        svalid, cval, cidx, ccnt);
  k_match<<<1, 256, 0, stream>>>(cval, cidx, ccnt, sscore, svalid, order, mtrack,
                                 ntptr, feats, out);
}

// Round 5
// 605.245 us; speedup vs baseline: 1.0637x; 1.0637x over previous
//
#include <hip/hip_runtime.h>

#define NDET 4096
#define NMEM 8192
#define DEMB 256
#define CAP  64
#define POOL 6144

static __device__ __forceinline__ float sim_val(float f, float rm, float rs,
                                                float cm, float cs, bool same) {
  if (!same) return 0.0f;
  return 0.5f * (expf(f - rm) / rs + expf(f - cm) / cs);
}

// ---------- 1. stable descending rank sort (+ ccnt zeroing) ----------
__global__ __launch_bounds__(256) void k_sort(const float* __restrict__ scores,
                                              const int* __restrict__ cls,
                                              const float* __restrict__ det,
                                              int* order, float* sscore, int* scls,
                                              float* sboxes, int* ccnt) {
  __shared__ float s[NDET];
  int tid = threadIdx.x;
  for (int i = tid; i < NDET; i += 256) s[i] = scores[i];
  __syncthreads();
  int i = blockIdx.x * 256 + tid;
  ccnt[i] = 0;
  float si = s[i];
  int rank = 0;
  for (int j = 0; j < NDET; ++j) {
    float sj = s[j];
    rank += (sj > si) || (sj == si && j < i);
  }
  order[rank] = i;
  sscore[rank] = si;
  scls[rank] = cls[i];
  ((float4*)sboxes)[rank] = ((const float4*)det)[i];
}

// ---------- 2. gather sorted embeddings ----------
__global__ __launch_bounds__(256) void k_gather(const float* __restrict__ emb,
                                                const int* __restrict__ order,
                                                float* A) {
  int idx = blockIdx.x * 256 + threadIdx.x;  // N*64 threads
  int r = idx >> 6, lane = idx & 63;
  int o = order[r];
  ((float4*)A)[(size_t)r * 64 + lane] = ((const float4*)emb)[(size_t)o * 64 + lane];
}

// ---------- 3. NMS validity (all j < i suppress, as in source) ----------
__global__ __launch_bounds__(256) void k_valid(const float* __restrict__ sbox,
                                               const float* __restrict__ sscore,
                                               int* svalid) {
  int i = blockIdx.x, tid = threadIdx.x;
  float4 bi = ((const float4*)sbox)[i];
  float thr = (sscore[i] < 0.3f) ? 0.3f : 0.7f;
  float ai = fmaxf(bi.z - bi.x, 0.f) * fmaxf(bi.w - bi.y, 0.f);
  __shared__ int flag;
  if (tid == 0) flag = 0;
  __syncthreads();
  int any = 0;
  for (int j = tid; j < i; j += 256) {
    float4 bj = ((const float4*)sbox)[j];
    float aj = fmaxf(bj.z - bj.x, 0.f) * fmaxf(bj.w - bj.y, 0.f);
    float lx = fmaxf(bi.x, bj.x), ly = fmaxf(bi.y, bj.y);
    float rx = fminf(bi.z, bj.z), ry = fminf(bi.w, bj.w);
    float w = fmaxf(rx - lx, 0.f), h = fmaxf(ry - ly, 0.f);
    float inter = w * h;
    float den = fmaxf(ai + aj - inter, 1e-6f);
    any |= ((inter / den) > thr);
  }
  if (any) atomicOr(&flag, 1);
  __syncthreads();
  if (tid == 0) svalid[i] = flag ? 0 : 1;
}

// ---------- 4. GEMM (feats into d_out sims region) + tile stats ----------
// LDS union: As/Bs (K-loop) alias red/tmax (epilogue) -> ~34 KB -> 4 blocks/CU.
__global__ __launch_bounds__(256, 4) void k_gemm1(const float* __restrict__ A,
                                                  const float* __restrict__ B,
                                                  const int* __restrict__ svalid,
                                                  float2* __restrict__ rowpart,
                                                  float2* __restrict__ colpart,
                                                  float* __restrict__ feats) {
  __shared__ float smraw[2 * 32 * 132];  // 33792 B
  float (*As)[132] = (float (*)[132])smraw;
  float (*Bs)[132] = (float (*)[132])(smraw + 32 * 132);
  float (*red)[17] = (float (*)[17])smraw;          // epilogue alias
  float* tmax = smraw + 128 * 17;                   // epilogue alias (2176..2303)
  __shared__ unsigned char vrow[128];
  const int tid = threadIdx.x;
  const int tx = tid & 15, ty = tid >> 4;
  const int j0 = blockIdx.x * 128, i0 = blockIdx.y * 128;
  if (tid < 128) vrow[tid] = (unsigned char)svalid[i0 + tid];
  float acc[8][8];
#pragma unroll
  for (int u = 0; u < 8; ++u)
#pragma unroll
    for (int v = 0; v < 8; ++v) acc[u][v] = 0.f;

  for (int kt = 0; kt < DEMB / 32; ++kt) {
    const int k0 = kt * 32;
    float4 av[4], bv[4];
    int rr[4], cc[4];
#pragma unroll
    for (int e = 0; e < 4; ++e) {
      int f = e * 256 + tid;
      rr[e] = f >> 3;
      cc[e] = (f & 7) << 2;
      av[e] = *(const float4*)(A + (size_t)(i0 + rr[e]) * DEMB + k0 + cc[e]);
      bv[e] = *(const float4*)(B + (size_t)(j0 + rr[e]) * DEMB + k0 + cc[e]);
    }
    __syncthreads();
#pragma unroll
    for (int e = 0; e < 4; ++e) {
      As[cc[e] + 0][rr[e]] = av[e].x;
      As[cc[e] + 1][rr[e]] = av[e].y;
      As[cc[e] + 2][rr[e]] = av[e].z;
      As[cc[e] + 3][rr[e]] = av[e].w;
      Bs[cc[e] + 0][rr[e]] = bv[e].x;
      Bs[cc[e] + 1][rr[e]] = bv[e].y;
      Bs[cc[e] + 2][rr[e]] = bv[e].z;
      Bs[cc[e] + 3][rr[e]] = bv[e].w;
    }
    __syncthreads();
#pragma unroll
    for (int kk = 0; kk < 32; ++kk) {
      float4 a0 = *(const float4*)&As[kk][ty * 8];
      float4 a1 = *(const float4*)&As[kk][ty * 8 + 4];
      float4 b0 = *(const float4*)&Bs[kk][tx * 8];
      float4 b1 = *(const float4*)&Bs[kk][tx * 8 + 4];
      float a[8] = {a0.x, a0.y, a0.z, a0.w, a1.x, a1.y, a1.z, a1.w};
      float b[8] = {b0.x, b0.y, b0.z, b0.w, b1.x, b1.y, b1.z, b1.w};
#pragma unroll
      for (int u = 0; u < 8; ++u)
#pragma unroll
        for (int v = 0; v < 8; ++v) acc[u][v] = __builtin_fmaf(a[u], b[v], acc[u][v]);
    }
  }
  // ---- store raw feats (fp32) into the sims output region ----
#pragma unroll
  for (int u = 0; u < 8; ++u) {
    int row = i0 + ty * 8 + u;
    float4 o0 = {acc[u][0], acc[u][1], acc[u][2], acc[u][3]};
    float4 o1 = {acc[u][4], acc[u][5], acc[u][6], acc[u][7]};
    *(float4*)(feats + (size_t)row * NMEM + j0 + tx * 8) = o0;
    *(float4*)(feats + (size_t)row * NMEM + j0 + tx * 8 + 4) = o1;
  }
  __syncthreads();  // K-loop LDS dead; epilogue aliases it now
  // ---- row stats: exact max-then-sum within tile ----
#pragma unroll
  for (int u = 0; u < 8; ++u) {
    float m = acc[u][0];
#pragma unroll
    for (int v = 1; v < 8; ++v) m = fmaxf(m, acc[u][v]);
    red[ty * 8 + u][tx] = m;
  }
  __syncthreads();
  if (tid < 128) {
    float m = red[tid][0];
#pragma unroll
    for (int t = 1; t < 16; ++t) m = fmaxf(m, red[tid][t]);
    tmax[tid] = m;
  }
  __syncthreads();
#pragma unroll
  for (int u = 0; u < 8; ++u) {
    float m = tmax[ty * 8 + u], s = 0.f;
#pragma unroll
    for (int v = 0; v < 8; ++v) s += expf(acc[u][v] - m);
    red[ty * 8 + u][tx] = s;
  }
  __syncthreads();
  if (tid < 128) {
    float s = 0.f;
#pragma unroll
    for (int t = 0; t < 16; ++t) s += red[tid][t];
    rowpart[(size_t)(i0 + tid) * 64 + blockIdx.x] = make_float2(tmax[tid], s);
  }
  __syncthreads();
  // ---- col stats: valid rows only ----
#pragma unroll
  for (int v = 0; v < 8; ++v) {
    float m = -INFINITY;
#pragma unroll
    for (int u = 0; u < 8; ++u)
      if (vrow[ty * 8 + u]) m = fmaxf(m, acc[u][v]);
    red[tx * 8 + v][ty] = m;
  }
  __syncthreads();
  if (tid < 128) {
    float m = red[tid][0];
#pragma unroll
    for (int t = 1; t < 16; ++t) m = fmaxf(m, red[tid][t]);
    tmax[tid] = m;
  }
  __syncthreads();
#pragma unroll
  for (int v = 0; v < 8; ++v) {
    float m = tmax[tx * 8 + v], s = 0.f;
    if (m > -INFINITY) {
#pragma unroll
      for (int u = 0; u < 8; ++u)
        if (vrow[ty * 8 + u]) s += expf(acc[u][v] - m);
    }
    red[tx * 8 + v][ty] = s;
  }
  __syncthreads();
  if (tid < 128) {
    float s = 0.f;
#pragma unroll
    for (int t = 0; t < 16; ++t) s += red[tid][t];
    colpart[(size_t)(j0 + tid) * 32 + blockIdx.y] = make_float2(tmax[tid], s);
  }
}

// ---------- 5. merge stats (fixed chunk order, deterministic) ----------
__global__ __launch_bounds__(256) void k_rowmerge(const float2* __restrict__ rowpart,
                                                  float* rmax, float* rsum) {
  int r = blockIdx.x * 256 + threadIdx.x;
  float M = -INFINITY;
  for (int c = 0; c < 64; ++c) M = fmaxf(M, rowpart[(size_t)r * 64 + c].x);
  float s = 0.f;
  for (int c = 0; c < 64; ++c) {
    float2 p = rowpart[(size_t)r * 64 + c];
    s += p.y * expf(p.x - M);
  }
  rmax[r] = M;
  rsum[r] = s;
}

__global__ __launch_bounds__(256) void k_colmerge(const float2* __restrict__ colpart,
                                                  float* cmax, float* csum) {
  int c = blockIdx.x * 256 + threadIdx.x;
  float M = -INFINITY;
  for (int b = 0; b < 32; ++b) {
    float2 p = colpart[(size_t)c * 32 + b];
    if (p.y > 0.f) M = fmaxf(M, p.x);
  }
  float s = 0.f;
  for (int b = 0; b < 32; ++b) {
    float2 p = colpart[(size_t)c * 32 + b];
    if (p.y > 0.f) s += p.y * expf(p.x - M);
  }
  cmax[c] = M;
  csum[c] = s;
}

// ---------- 6. in-place transform feats -> sims (fp32) + candidates ----------
__global__ __launch_bounds__(256) void k_transform(float* __restrict__ sims,
                                                   const float* __restrict__ rmax,
                                                   const float* __restrict__ rsum,
                                                   const float* __restrict__ cmax,
                                                   const float* __restrict__ csum,
                                                   const int* __restrict__ scls,
                                                   const int* __restrict__ mcls,
                                                   const int* __restrict__ svalid,
                                                   float* __restrict__ cval,
                                                   int* __restrict__ cidx,
                                                   int* __restrict__ ccnt) {
  const int r = blockIdx.x, tid = threadIdx.x;
  float* row = sims + (size_t)r * NMEM;
  if (!svalid[r]) {
    float4 z = {0.f, 0.f, 0.f, 0.f};
#pragma unroll
    for (int it = 0; it < 8; ++it) *(float4*)(row + it * 1024 + tid * 4) = z;
    return;
  }
  const float rm = rmax[r], rs = rsum[r];
  const int rc = scls[r];
#pragma unroll
  for (int it = 0; it < 8; ++it) {
    int j = it * 1024 + tid * 4;
    float4 f = *(const float4*)(row + j);
    float4 cm4 = *(const float4*)(cmax + j);
    float4 cs4 = *(const float4*)(csum + j);
    int4 mc4 = *(const int4*)(mcls + j);
    float4 o;
    o.x = sim_val(f.x, rm, rs, cm4.x, cs4.x, rc == mc4.x);
    o.y = sim_val(f.y, rm, rs, cm4.y, cs4.y, rc == mc4.y);
    o.z = sim_val(f.z, rm, rs, cm4.z, cs4.z, rc == mc4.z);
    o.w = sim_val(f.w, rm, rs, cm4.w, cs4.w, rc == mc4.w);
    *(float4*)(row + j) = o;
    float vs[4] = {o.x, o.y, o.z, o.w};
#pragma unroll
    for (int q = 0; q < 4; ++q) {
      if (vs[q] > 0.5f) {
        int ps = atomicAdd(&ccnt[r], 1);
        if (ps < CAP) {
          cval[(size_t)r * CAP + ps] = vs[q];
          cidx[(size_t)r * CAP + ps] = j + q;
        }
      }
    }
  }
}

// ---------- 7. greedy matching, fully LDS-resident serial loop ----------
__global__ __launch_bounds__(256) void k_match(
    const float* __restrict__ cval, const int* __restrict__ cidx,
    const int* __restrict__ ccnt, const float* __restrict__ sscore,
    const int* __restrict__ svalid, const int* __restrict__ order,
    const int* __restrict__ mtrack, const int* __restrict__ ntptr,
    const float* __restrict__ sims, float* __restrict__ out) {
  const int tid = threadIdx.x;
  __shared__ float pv[POOL];                 // 24 KB candidate vals
  __shared__ int mt[NMEM];                   // 32 KB memo track ids
  __shared__ int ids_s[NDET];                // 16 KB
  __shared__ unsigned int taken[NMEM / 32];  // 1 KB
  __shared__ int part[256];
  __shared__ float rv[256];
  __shared__ int ri[256];
  __shared__ unsigned short pi[POOL];        // 12 KB candidate idx
  __shared__ unsigned short rlist[NDET];     // 8 KB
  __shared__ unsigned short cstart[NDET];    // 8 KB
  __shared__ unsigned char flags[NDET];      // 4 KB: valid|strong<<1|init<<2
  __shared__ unsigned char cnt_s[NDET];      // 4 KB
  __shared__ int nR_s;

  // phase A: load control state (coalesced)
  for (int r = tid; r < NDET; r += 256) {
    float s = sscore[r];
    int c = ccnt[r];
    flags[r] = (unsigned char)((svalid[r] ? 1 : 0) | (s > 0.3f ? 2 : 0) |
                               (s > 0.7f ? 4 : 0));
    cnt_s[r] = (unsigned char)(c > 255 ? 255 : c);
    ids_s[r] = -1;
  }
  for (int j = tid; j < NMEM; j += 256) mt[j] = mtrack[j];
  taken[tid] = 0u;
  __syncthreads();

  // phase B: rlist (ascending r) + pool offsets
  const int base = tid * 16;
  int cn = 0, pool_need = 0;
  for (int k = 0; k < 16; ++k) {
    int c = cnt_s[base + k];
    cn += (c > 0);
    pool_need += (c > 0 && c <= CAP) ? c : 0;
  }
  part[tid] = cn;
  __syncthreads();
  if (tid == 0) {
    int run = 0;
    for (int t = 0; t < 256; ++t) { int v = part[t]; part[t] = run; run += v; }
    nR_s = run;
  }
  __syncthreads();
  {
    int pos = part[tid];
    for (int k = 0; k < 16; ++k)
      if (cnt_s[base + k] > 0) rlist[pos++] = (unsigned short)(base + k);
  }
  __syncthreads();
  part[tid] = pool_need;
  __syncthreads();
  if (tid == 0) {
    int run = 0;
    for (int t = 0; t < 256; ++t) { int v = part[t]; part[t] = run; run += v; }
  }
  __syncthreads();
  // phase C: copy candidates into LDS pool
  {
    int off = part[tid];
    for (int k = 0; k < 16; ++k) {
      int r = base + k;
      int c = cnt_s[r];
      if (c == 0) continue;
      if (c <= CAP) {
        if (off + c <= POOL) {
          cstart[r] = (unsigned short)off;
          for (int q = 0; q < c; ++q) {
            pv[off + q] = cval[(size_t)r * CAP + q];
            pi[off + q] = (unsigned short)cidx[(size_t)r * CAP + q];
          }
        } else cstart[r] = 0xFFFFu;
        off += c;
      } else cstart[r] = 0xFFFFu;
    }
  }
  __syncthreads();
  const int nR = nR_s;

  // phase D: serial greedy (LDS only on fast path)
  for (int t = 0; t < nR; ++t) {
    const int r = rlist[t];
    const int c = cnt_s[r];
    if (c <= CAP) {
      if (tid == 0) {
        float bvv = 0.f;
        int bii = -1;
        const unsigned int st = cstart[r];
        if (st != 0xFFFFu) {
          for (int q = 0; q < c; ++q) {
            int j = pi[st + q];
            if ((taken[j >> 5] >> (j & 31)) & 1u) continue;
            float v = pv[st + q];
            if (bii < 0 || v > bvv || (v == bvv && j < bii)) { bvv = v; bii = j; }
          }
        } else {
          for (int q = 0; q < c; ++q) {
            int j = cidx[(size_t)r * CAP + q];
            if ((taken[j >> 5] >> (j & 31)) & 1u) continue;
            float v = cval[(size_t)r * CAP + q];
            if (bii < 0 || v > bvv || (v == bvv && j < bii)) { bvv = v; bii = j; }
          }
        }
        if (bii >= 0 && bvv > 0.5f) {
          int cur = mt[bii];
          if (cur > -1) {
            if (flags[r] & 2) { ids_s[r] = cur; taken[bii >> 5] |= 1u << (bii & 31); }
          } else ids_s[r] = -2;
        }
      }
    } else {
      __syncthreads();  // make tid0's taken/ids writes visible
      const float* srow = sims + (size_t)r * NMEM;
      float bvv = -1.f;
      int bii = 1 << 30;
      for (int j = tid; j < NMEM; j += 256) {
        float v = ((taken[j >> 5] >> (j & 31)) & 1u) ? 0.f : srow[j];
        if (v > bvv || (v == bvv && j < bii)) { bvv = v; bii = j; }
      }
      rv[tid] = bvv;
      ri[tid] = bii;
      __syncthreads();
      for (int off = 128; off > 0; off >>= 1) {
        if (tid < off) {
          float v2 = rv[tid + off];
          int i2 = ri[tid + off];
          if (v2 > rv[tid] || (v2 == rv[tid] && i2 < ri[tid])) { rv[tid] = v2; ri[tid] = i2; }
        }
        __syncthreads();
      }
      if (tid == 0) {
        float conf = rv[0];
        int ind = ri[0];
        if (conf > 0.5f) {
          int cur = mt[ind];
          if (cur > -1) {
            if (flags[r] & 2) { ids_s[r] = cur; taken[ind >> 5] |= 1u << (ind & 31); }
          } else ids_s[r] = -2;
        }
      }
      __syncthreads();
    }
  }
  __syncthreads();

  // phase E: new tracks (cumsum over sorted order), then un-permute
  int cntNew = 0;
  for (int k = 0; k < 16; ++k) {
    int r = base + k;
    cntNew += (ids_s[r] == -1 && (flags[r] & 4) && (flags[r] & 1));
  }
  part[tid] = cntNew;
  __syncthreads();
  if (tid == 0) {
    int run = 0;
    for (int t2 = 0; t2 < 256; ++t2) { int v = part[t2]; part[t2] = run; run += v; }
  }
  __syncthreads();
  const int nt = ntptr[0];
  int off2 = part[tid];
  for (int k = 0; k < 16; ++k) {
    int r = base + k;
    if (ids_s[r] == -1 && (flags[r] & 4) && (flags[r] & 1)) ids_s[r] = nt + off2++;
  }
  __syncthreads();
  for (int r = tid; r < NDET; r += 256) {
    int o = order[r];
    out[o] = (float)ids_s[r];
    out[NDET + o] = (flags[r] & 1) ? 1.0f : 0.0f;
  }
}

extern "C" void kernel_launch(void* const* d_in, const int* in_sizes, int n_in,
                              void* d_out, int out_size, void* d_ws, size_t ws_size,
                              hipStream_t stream) {
  const float* det = (const float*)d_in[0];
  const float* scores = (const float*)d_in[1];
  const int* cls = (const int*)d_in[2];
  const float* emb = (const float*)d_in[3];
  const float* memo = (const float*)d_in[4];
  const int* mcls = (const int*)d_in[5];
  const int* mtrack = (const int*)d_in[6];
  const int* ntptr = (const int*)d_in[7];
  float* out = (float*)d_out;     // fp32 outputs: [ids | valid | sims]
  float* feats = out + 2 * NDET;  // sims region doubles as feats scratch

  // ---- workspace: ~10.25 MB ----
  char* ws = (char*)d_ws;
  size_t o_A = 0;                                        // 4 MB
  size_t o_order = o_A + (size_t)NDET * DEMB * 4;
  size_t o_sscore = o_order + NDET * 4;
  size_t o_scls = o_sscore + NDET * 4;
  size_t o_svalid = o_scls + NDET * 4;
  size_t o_sbox = o_svalid + NDET * 4;
  size_t o_rowpart = o_sbox + NDET * 16;                 // 2 MB
  size_t o_colpart = o_rowpart + (size_t)NDET * 64 * 8;  // 2 MB
  size_t o_rmax = o_colpart + (size_t)NMEM * 32 * 8;
  size_t o_rsum = o_rmax + NDET * 4;
  size_t o_cmax = o_rsum + NDET * 4;
  size_t o_csum = o_cmax + NMEM * 4;
  size_t o_cval = o_csum + NMEM * 4;                     // 1 MB
  size_t o_cidx = o_cval + (size_t)NDET * CAP * 4;       // 1 MB
  size_t o_ccnt = o_cidx + (size_t)NDET * CAP * 4;       // 16 KB

  float* A = (float*)(ws + o_A);
  int* order = (int*)(ws + o_order);
  float* sscore = (float*)(ws + o_sscore);
  int* scls = (int*)(ws + o_scls);
  int* svalid = (int*)(ws + o_svalid);
  float* sbox = (float*)(ws + o_sbox);
  float2* rowpart = (float2*)(ws + o_rowpart);
  float2* colpart = (float2*)(ws + o_colpart);
  float* rmax = (float*)(ws + o_rmax);
  float* rsum = (float*)(ws + o_rsum);
  float* cmax = (float*)(ws + o_cmax);
  float* csum = (float*)(ws + o_csum);
  float* cval = (float*)(ws + o_cval);
  int* cidx = (int*)(ws + o_cidx);
  int* ccnt = (int*)(ws + o_ccnt);

  k_sort<<<NDET / 256, 256, 0, stream>>>(scores, cls, det, order, sscore, scls, sbox,
                                         ccnt);
  k_gather<<<NDET * 64 / 256, 256, 0, stream>>>(emb, order, A);
  k_valid<<<NDET, 256, 0, stream>>>(sbox, sscore, svalid);
  k_gemm1<<<dim3(NMEM / 128, NDET / 128), 256, 0, stream>>>(A, memo, svalid, rowpart,
                                                            colpart, feats);
  k_rowmerge<<<NDET / 256, 256, 0, stream>>>(rowpart, rmax, rsum);
  k_colmerge<<<NMEM / 256, 256, 0, stream>>>(colpart, cmax, csum);
  k_transform<<<NDET, 256, 0, stream>>>(feats, rmax, rsum, cmax, csum, scls, mcls,
                                        svalid, cval, cidx, ccnt);
  k_match<<<1, 256, 0, stream>>>(cval, cidx, ccnt, sscore, svalid, order, mtrack,
                                 ntptr, feats, out);
}